// Round 4
// baseline (1276.919 us; speedup 1.0000x reference)
//
#include <hip/hip_runtime.h>

typedef unsigned long long u64;
#define THRESH 0.5f
#define ALL1 0xFFFFFFFFFFFFFFFFull
#define CAP 256      // eviction-window capacity (exact bottom-m of pool)
#define STAGE 320    // rebuild candidate staging capacity

__device__ __forceinline__ float keyVal(u64 k) { return __uint_as_float((unsigned)(k >> 32)); }
__device__ __forceinline__ u64 packKey(float v, int slot) {
    return ((u64)__float_as_uint(v) << 32) | (unsigned)slot;
}
__device__ __forceinline__ float waveMinF(float v) {
#pragma unroll
    for (int off = 1; off < 64; off <<= 1) v = fminf(v, __shfl_xor(v, off, 64));
    return v;
}
__device__ __forceinline__ float waveMaxF(float v) {
#pragma unroll
    for (int off = 1; off < 64; off <<= 1) v = fmaxf(v, __shfl_xor(v, off, 64));
    return v;
}
// Wave sum of small per-lane counts via ballots (no LDS-pipe shuffles).
__device__ __forceinline__ int waveSumB(int c, int bits) {
    int s = 0;
    for (int b = 0; b < bits; ++b)
        s += (int)__popcll(__ballot((c >> b) & 1)) << b;
    return s;
}
__device__ __forceinline__ int wavePrefixExclB(int c, u64 laneLt, int bits, int &tot) {
    int p = 0; tot = 0;
    for (int b = 0; b < bits; ++b) {
        u64 bl = __ballot((c >> b) & 1);
        p += (int)__popcll(bl & laneLt) << b;
        tot += (int)__popcll(bl) << b;
    }
    return p;
}
// Shift window entries [q0,q1) down by one absolute slot. All-lane call;
// reads complete (reg deps) before writes issue; LDS is in-order per wave.
__device__ __forceinline__ void shiftDown(u64* w, int absBase, int q0, int q1, int lane) {
    u64 t[4]; int n = 0;
    for (int q = absBase + q0 + lane; q < absBase + q1; q += 64) t[n++] = w[q];
    n = 0;
    for (int q = absBase + q0 + lane; q < absBase + q1; q += 64) w[q - 1] = t[n++];
}

// Rebuild bufB[0..m) = exact bottom-m of pool (key = (valueBits,slot)),
// sorted ascending, m in [64, CAP]. No bitonic sorts: rank-scatter.
__device__ void rebuildWindow(const float* pr, u64* cand, u64* bufB, int lane,
                              int &bOff, int &m, float &curMinVal) {
    const u64 laneLt = (1ull << lane) - 1;
    // pool -> regs: lane holds slots 256*i + 4*lane .. +3
    float4 v[16];
#pragma unroll
    for (int i = 0; i < 16; ++i) v[i] = ((const float4*)pr)[(i << 6) + lane];

    float mn = __builtin_inff();
#pragma unroll
    for (int i = 0; i < 16; ++i)
        mn = fminf(mn, fminf(fminf(v[i].x, v[i].y), fminf(v[i].z, v[i].w)));
    float lo = waveMinF(mn);
    float hi = waveMaxF(mn);   // count(<=hi) >= 64 guaranteed
    if (curMinVal > lo && curMinVal < hi) lo = curMinVal;  // stale lower bound

    int cHi = 0;
#pragma unroll
    for (int i = 0; i < 16; ++i)
        cHi += (v[i].x <= hi) + (v[i].y <= hi) + (v[i].z <= hi) + (v[i].w <= hi);
    cHi = waveSumB(cHi, 7);

    // interpolation search for pivot with count in [64, CAP]
    for (int it = 0; it < 8 && cHi > CAP; ++it) {
        float mid = lo + (hi - lo) * (160.0f / (float)cHi);
        if (!(mid > lo && mid < hi)) break;
        int c = 0;
#pragma unroll
        for (int i = 0; i < 16; ++i)
            c += (v[i].x <= mid) + (v[i].y <= mid) + (v[i].z <= mid) + (v[i].w <= mid);
        c = waveSumB(c, 7);
        if (c >= 64) { hi = mid; cHi = c; } else lo = mid;
    }

    // compact candidates (<= hi) into cand[] via ballot prefix
    int myc = 0;
#pragma unroll
    for (int i = 0; i < 16; ++i)
        myc += (v[i].x <= hi) + (v[i].y <= hi) + (v[i].z <= hi) + (v[i].w <= hi);
    int tot;
    int off = wavePrefixExclB(myc, laneLt, 7, tot);
    int nc = tot;   // >= 64; normally <= CAP (STAGE guard is overflow safety)
#pragma unroll
    for (int i = 0; i < 16; ++i) {
        int slot = (i << 8) + (lane << 2);
        float x;
        x = v[i].x; if (x <= hi && off < STAGE) cand[off++] = packKey(x, slot);
        x = v[i].y; if (x <= hi && off < STAGE) cand[off++] = packKey(x, slot + 1);
        x = v[i].z; if (x <= hi && off < STAGE) cand[off++] = packKey(x, slot + 2);
        x = v[i].w; if (x <= hi && off < STAGE) cand[off++] = packKey(x, slot + 3);
    }
    if (nc > STAGE) nc = STAGE;
    if (lane == 0 && (nc & 1)) cand[nc] = ALL1;  // pad for b128 reads
    int ncp = (nc + 1) & ~1;

    // rank sort: lane owns cand[lane + 64t]; rank = #cands with smaller key
    u64 myk[5]; int rk[5]; int nmine = 0;
    for (int t = lane; t < nc; t += 64) { myk[nmine] = cand[t]; rk[nmine] = 0; ++nmine; }
    for (int q = 0; q < ncp; q += 2) {
        ulonglong2 c2 = *((const ulonglong2*)(cand + q));  // broadcast read
        for (int a = 0; a < nmine; ++a)
            rk[a] += (int)(c2.x < myk[a]) + (int)(c2.y < myk[a]);
    }
    for (int a = 0; a < nmine; ++a)
        if (rk[a] < CAP) bufB[rk[a]] = myk[a];

    bOff = 0;
    m = (nc < CAP) ? nc : CAP;
    curMinVal = keyVal(bufB[0]);   // in-order LDS pipe: writes above visible
}

__global__ __launch_bounds__(64, 1) void sim_kernel(
    const float* __restrict__ scores,
    const float* __restrict__ priorities,
    const int* __restrict__ countPtr,
    int N, int P,
    float* __restrict__ outPrior,
    float* __restrict__ outCnt,
    int* __restrict__ srcOut)
{
    __shared__ __align__(16) float pr[4096];
    __shared__ int srcLds[4096];
    __shared__ __align__(16) u64 bufB[CAP];
    __shared__ __align__(16) u64 cand[STAGE + 2];
    const int lane = threadIdx.x;
    const u64 laneBit = 1ull << lane;
    const u64 laneLt = laneBit - 1;

    for (int k = lane; k < P; k += 64) { pr[k] = priorities[k]; srcLds[k] = -1; }
    __syncthreads();

    int cnt = *countPtr;
    int bOff = 0, m = 0;
    float curMinVal = -__builtin_inff();   // stale-safe lower bound of pool min

    float sc_l = (lane < N) ? scores[lane] : 0.f;
    for (int base = 0; base < N; base += 64) {
        float sc = sc_l;
        if (base + 64 + lane < N) sc_l = scores[base + 64 + lane];  // prefetch
        u64 mask = __ballot(sc > THRESH);
        if (!mask) continue;

        if (cnt < P) {
            // batched append: first nApp valid lanes take slots cnt..cnt+nApp-1
            int k = (int)__popcll(mask);
            int nApp = P - cnt; if (nApp > k) nApp = k;
            bool val_l = (mask & laneBit) != 0;
            int pos = (int)__popcll(mask & laneLt);
            bool doApp = val_l && (pos < nApp);
            if (doApp) { pr[cnt + pos] = sc; srcLds[cnt + pos] = base + lane; }
            mask &= ~__ballot(doApp);
            cnt += nApp;
            if (!mask) continue;
        }

        // replacement phase (pool full)
        mask &= __ballot(sc > curMinVal);
        while (mask) {
            int k = (int)__popcll(mask);
            if (m < k) {
                rebuildWindow(pr, cand, bufB, lane, bOff, m, curMinVal);
                mask &= __ballot(sc > curMinVal);
                if (!mask) break;
                k = (int)__popcll(mask);
            }
            float tv = keyVal(bufB[bOff + k - 1]);   // broadcast LDS read
            u64 okb = __ballot(sc > tv);
            if ((okb & mask) == mask) {
                // FAST PATH: all k inserters > B[k-1] -> evict B[0..k-1] in
                // rank order, fully parallel, zero shuffles.
                bool ins = (mask & laneBit) != 0;
                int r = (int)__popcll(mask & laneLt);
                u64 be = bufB[bOff + (ins ? r : 0)];
                int slot = (int)(be & 0xFFFFFFFFu);
                if (ins) { pr[slot] = sc; srcLds[slot] = base + lane; }
                bOff += k; m -= k;
                if (m > 0) {
                    u64 mykey = packKey(sc, slot);
                    u64 bmax = bufB[bOff + m - 1];
                    u64 smask = __ballot(ins && (mykey < bmax));
                    while (smask) {   // rare: inserted key inside window band
                        int j = __ffsll(smask) - 1; smask &= smask - 1;
                        u64 kk = ((u64)(unsigned)__shfl((int)(mykey >> 32), j, 64) << 32)
                               | (unsigned)__shfl((int)mykey, j, 64);
                        int cl = 0;
                        for (int q = lane; q < m; q += 64) cl += (bufB[bOff + q] < kk) ? 1 : 0;
                        int p = waveSumB(cl, 3);
                        if (p < m) {
                            if (m == CAP) m--;              // drop max, keep exactness
                            shiftDown(bufB, bOff, 0, p, lane);
                            if (lane == 0) bufB[bOff + p - 1] = kk;
                            bOff -= 1; m += 1;
                        }
                    }
                    curMinVal = keyVal(bufB[bOff]);
                }
                // m==0: leave curMinVal stale (safe); loop-top rebuilds lazily
                mask = 0;
            } else {
                // SERIAL: lowest masked item — evict B[0], maybe insert key.
                int j = __ffsll(mask) - 1; mask &= mask - 1;
                float scj = __shfl(sc, j, 64);
                if (scj > curMinVal) {
                    u64 b0 = bufB[bOff];
                    int widx = (int)(b0 & 0xFFFFFFFFu);
                    if (lane == 0) { pr[widx] = scj; srcLds[widx] = base + j; }
                    u64 key = packKey(scj, widx);
                    int cl = 0;
                    for (int q = lane; q < m; q += 64) cl += (bufB[bOff + q] < key) ? 1 : 0;
                    int p = waveSumB(cl, 3);    // >= 1 since B[0] < key
                    if (p < m) {
                        // remove B[0], insert at rank p-1: coverage stays exact
                        shiftDown(bufB, bOff, 1, p, lane);
                        if (lane == 0) bufB[bOff + p - 1] = key;
                    } else {
                        bOff += 1; m -= 1;      // key beyond coverage: drop B[0]
                    }
                    if (m > 0) curMinVal = keyVal(bufB[bOff]);
                    mask &= __ballot(sc > curMinVal);
                }
            }
        }
    }

    __syncthreads();
    for (int k = lane; k < P; k += 64) { outPrior[k] = pr[k]; srcOut[k] = srcLds[k]; }
    if (lane == 0) outCnt[0] = (float)cnt;
}

// Fully parallel pool materialization: one block per slot row.
__global__ __launch_bounds__(256) void gather_kernel(
    const float* __restrict__ summaries,
    const float* __restrict__ pool,
    const int* __restrict__ src,
    float* __restrict__ outPool, int D) {
    int p = blockIdx.x;
    int s = src[p];
    const float* row = (s >= 0) ? (summaries + (size_t)s * D) : (pool + (size_t)p * D);
    float* o = outPool + (size_t)p * D;
    if ((D & 3) == 0) {
        for (int k = (threadIdx.x << 2); k < D; k += (blockDim.x << 2)) {
            float4 v = *(const float4*)(row + k);
            *(float4*)(o + k) = v;
        }
    } else {
        for (int k = threadIdx.x; k < D; k += blockDim.x) o[k] = row[k];
    }
}

extern "C" void kernel_launch(void* const* d_in, const int* in_sizes, int n_in,
                              void* d_out, int out_size, void* d_ws, size_t ws_size,
                              hipStream_t stream) {
    const float* summaries  = (const float*)d_in[0];
    const float* scores     = (const float*)d_in[1];
    const float* pool       = (const float*)d_in[2];
    const float* priorities = (const float*)d_in[3];
    const int*   count      = (const int*)d_in[4];

    int N = in_sizes[1];            // 16384
    int P = in_sizes[3];            // 4096
    int D = in_sizes[0] / N;        // 1024

    float* outPool  = (float*)d_out;
    float* outPrior = outPool + (size_t)P * D;
    float* outCnt   = outPrior + P;
    int*   src      = (int*)d_ws;   // P ints of scratch

    sim_kernel<<<1, 64, 0, stream>>>(scores, priorities, count, N, P,
                                     outPrior, outCnt, src);
    gather_kernel<<<P, 256, 0, stream>>>(summaries, pool, src, outPool, D);
}